// Round 9
// baseline (199.494 us; speedup 1.0000x reference)
//
#include <hip/hip_runtime.h>

// SupConLoss, B=4096 D=256 L=20, T=0.07.
// Symmetric-triangle GEMM (C = F F^T computed once per unordered tile pair):
//   off-diag tile (I,J): row-side reduce -> rows I, col-side reduce -> rows J.
// Per-row max (MP, ordered-uint atomicMax) and stabilized expsum (EP, atomicAdd; es
// underflows to 0 exactly as the fp32 reference does).
// Loss factorization per (l,v) bucket: sum_i me_i = INVT*||Wt[l,v]||^2 - sum_i c_i,
// so k_final only buckets (lp_i + m_i) and c_i  -> O(B*L) + tiny norm pass.

#define INVT 14.285714285714286f

// ws layout (bytes). memset spans [0x10000, 0x32000).
#define CNT_OFF  0x004000u  // int [20][5]   (fully written by counts blocks)
#define WT_OFF   0x010000u  // f32 [100][256] atomic-accumulated (memset 0)
#define ACC_OFF  0x029000u  // f32 LPM[100], C[100], u32 done @+800 (memset 0)
#define MP_OFF   0x02A000u  // u32 [4096] ordered-float row max (memset 0 < ordf(x) for all x)
#define EP_OFF   0x02E000u  // f32 [4096] row expsum (memset 0)
#define CV_OFF   0x032000u  // f32 [4096] c_i, S units (fully written by diag blocks)

typedef __bf16 bf16x8 __attribute__((ext_vector_type(8)));
typedef float f32x4 __attribute__((ext_vector_type(4)));

struct __align__(16) U4 { unsigned int x, y, z, w; };

__device__ __forceinline__ U4 pack8(float4 a, float4 b) {
  bf16x8 v;
  v[0] = (__bf16)a.x; v[1] = (__bf16)a.y; v[2] = (__bf16)a.z; v[3] = (__bf16)a.w;
  v[4] = (__bf16)b.x; v[5] = (__bf16)b.y; v[6] = (__bf16)b.z; v[7] = (__bf16)b.w;
  return __builtin_bit_cast(U4, v);
}

__device__ __forceinline__ unsigned int ordf(float x) {  // monotone float->uint
  unsigned int u = __float_as_uint(x);
  return (u & 0x80000000u) ? ~u : (u | 0x80000000u);
}
__device__ __forceinline__ float ordinv(unsigned int o) {
  return __uint_as_float((o & 0x80000000u) ? (o & 0x7FFFFFFFu) : ~o);
}

// stage one 256-row x 128-k panel half: fp32 -> bf16, swizzled (write pattern mirrors
// the read pattern: every 16-lane quarter covers all 8 bank-groups twice).
__device__ __forceinline__ void stage_panel(const float* __restrict__ F, int gbase, int kh,
                                            unsigned char* lds, int w, int lr, int lg,
                                            float& s0, float& s1) {
  #pragma unroll
  for (int j = 0; j < 8; ++j) {
    const int rloc = w * 32 + ((j & 1) << 4) + lr;
    const int slot = ((j >> 1) << 2) + lg;
    const float* src = F + (size_t)(gbase + rloc) * 256 + kh * 128 + slot * 8;
    float4 f0 = *(const float4*)src;
    float4 f1 = *(const float4*)(src + 4);
    float ss = f0.x*f0.x + f0.y*f0.y + f0.z*f0.z + f0.w*f0.w
             + f1.x*f1.x + f1.y*f1.y + f1.z*f1.z + f1.w*f1.w;
    if (j & 1) s1 += ss; else s0 += ss;
    *(U4*)(lds + rloc * 256 + ((slot ^ (lr & 7)) << 4)) = pack8(f0, f1);
  }
}

// ---- fused: triangle GEMM (0..135) | counts (136..155) | Wt build (156..315) ----
__global__ __launch_bounds__(512, 2) void k_fused(const float* __restrict__ F,
                                                  const int* __restrict__ lab,
                                                  unsigned char* __restrict__ ws) {
  __shared__ unsigned char smem[133632];  // pA 64K | pB 64K | scvA 1K | scvB 1K
  const int bid = blockIdx.x, t = threadIdx.x;
  if (bid < 136) {
    const int w = t >> 6, l = t & 63, lr = l & 15, lg = l >> 4;
    int I = (int)((sqrtf(8.f * bid + 1.f) - 1.f) * 0.5f);
    if ((I + 1) * (I + 2) / 2 <= bid) ++I;
    if (I * (I + 1) / 2 > bid) --I;
    const int J = bid - I * (I + 1) / 2;
    const bool diag = (I == J);
    unsigned char* pA = smem;
    unsigned char* pB = diag ? smem : smem + 65536;
    float* scvA = (float*)(smem + 131072);
    float* scvB = diag ? scvA : scvA + 256;
    const int wr = w >> 1, wc = w & 1;
    float sA0 = 0, sA1 = 0, sB0 = 0, sB1 = 0;
    f32x4 acc[4][8] = {};
    #pragma unroll 1
    for (int kh = 0; kh < 2; ++kh) {
      if (kh) __syncthreads();  // protect prev-half LDS reads before overwrite
      stage_panel(F, I * 256, kh, pA, w, lr, lg, sA0, sA1);
      if (!diag) stage_panel(F, J * 256, kh, pB, w, lr, lg, sB0, sB1);
      __syncthreads();
      #pragma unroll 1
      for (int kk = 0; kk < 4; ++kk) {
        const int sx = ((kk * 4 + lg) ^ (lr & 7)) << 4;
        bf16x8 afr[4];
        #pragma unroll
        for (int mi = 0; mi < 4; ++mi)
          afr[mi] = *(bf16x8*)(pA + (wr * 64 + mi * 16 + lr) * 256 + sx);
        #pragma unroll
        for (int nh = 0; nh < 2; ++nh) {
          bf16x8 bfr[4];
          #pragma unroll
          for (int nn = 0; nn < 4; ++nn)
            bfr[nn] = *(bf16x8*)(pB + (wc * 128 + (nh * 4 + nn) * 16 + lr) * 256 + sx);
          #pragma unroll
          for (int mi = 0; mi < 4; ++mi)
            #pragma unroll
            for (int nn = 0; nn < 4; ++nn)
              acc[mi][nh * 4 + nn] =
                  __builtin_amdgcn_mfma_f32_16x16x32_bf16(afr[mi], bfr[nn], acc[mi][nh * 4 + nn], 0, 0, 0);
        }
      }
    }
    // per-row sumsq: threads (w,lr,lg=0..3) hold slot-partials of the same rows
    sA0 += __shfl_xor(sA0, 16, 64); sA0 += __shfl_xor(sA0, 32, 64);
    sA1 += __shfl_xor(sA1, 16, 64); sA1 += __shfl_xor(sA1, 32, 64);
    if (!diag) {
      sB0 += __shfl_xor(sB0, 16, 64); sB0 += __shfl_xor(sB0, 32, 64);
      sB1 += __shfl_xor(sB1, 16, 64); sB1 += __shfl_xor(sB1, 32, 64);
    }
    if (lg == 0) {
      scvA[w * 32 + lr] = sA0;
      scvA[w * 32 + 16 + lr] = sA1;
      if (!diag) { scvB[w * 32 + lr] = sB0; scvB[w * 32 + 16 + lr] = sB1; }
    }
    __syncthreads();
    if (diag && t < 256) ((float*)(ws + CV_OFF))[I * 256 + t] = scvA[t] * INVT;
    unsigned int* MP = (unsigned int*)(ws + MP_OFF);
    float* EP = (float*)(ws + EP_OFF);
    // row-side: rows I*256 + wr*64 + ..., reduced over this wave's 128 cols
    #pragma unroll 1
    for (int mi = 0; mi < 4; ++mi) {
      #pragma unroll
      for (int r = 0; r < 4; ++r) {
        const int lrow = wr * 64 + mi * 16 + lg * 4 + r;
        const int grow = I * 256 + lrow;
        const float crow = scvA[lrow] * INVT;
        float vm = -3.4e38f, es = 0.f;
        #pragma unroll
        for (int n = 0; n < 8; ++n) {
          const int gcol = J * 256 + wc * 128 + n * 16 + lr;
          const float v = acc[mi][n][r] * INVT;
          vm = fmaxf(vm, v);
          const float e0 = __expf(v - crow);
          es += (gcol == grow) ? 0.f : e0;  // diag exclusion (only possible when I==J)
        }
        #pragma unroll
        for (int off = 1; off < 16; off <<= 1) {
          vm = fmaxf(vm, __shfl_xor(vm, off, 16));
          es += __shfl_xor(es, off, 16);
        }
        if (lr == 0) { atomicMax(MP + grow, ordf(vm)); atomicAdd(EP + grow, es); }
      }
    }
    // col-side (off-diag only): rows J*256 + wc*128 + ..., reduced over this wave's 64 rows
    if (!diag) {
      #pragma unroll 1
      for (int n = 0; n < 8; ++n) {
        const int lcol = wc * 128 + n * 16 + lr;
        const int gcol = J * 256 + lcol;
        const float ccol = scvB[lcol] * INVT;
        float vm = -3.4e38f, es = 0.f;
        #pragma unroll
        for (int mi = 0; mi < 4; ++mi)
          #pragma unroll
          for (int r = 0; r < 4; ++r) {
            const float v = acc[mi][n][r] * INVT;
            vm = fmaxf(vm, v);
            es += __expf(v - ccol);
          }
        vm = fmaxf(vm, __shfl_xor(vm, 16, 64));
        vm = fmaxf(vm, __shfl_xor(vm, 32, 64));
        es += __shfl_xor(es, 16, 64);
        es += __shfl_xor(es, 32, 64);
        if (lg == 0) { atomicMax(MP + gcol, ordf(vm)); atomicAdd(EP + gcol, es); }
      }
    }
  } else if (bid < 156) {
    // counts[l][v], 512 threads
    int* sc = (int*)smem;  // [8][5]
    const int ll = bid - 136;
    int c0 = 0, c1 = 0, c2 = 0, c3 = 0, c4 = 0;
    for (int j = t; j < 4096; j += 512) {
      int v = lab[j * 20 + ll];
      c0 += (v == 0); c1 += (v == 1); c2 += (v == 2); c3 += (v == 3); c4 += (v == 4);
    }
    #pragma unroll
    for (int off = 1; off < 64; off <<= 1) {
      c0 += __shfl_xor(c0, off, 64); c1 += __shfl_xor(c1, off, 64);
      c2 += __shfl_xor(c2, off, 64); c3 += __shfl_xor(c3, off, 64);
      c4 += __shfl_xor(c4, off, 64);
    }
    const int w = t >> 6;
    if ((t & 63) == 0) { sc[w*5+0] = c0; sc[w*5+1] = c1; sc[w*5+2] = c2; sc[w*5+3] = c3; sc[w*5+4] = c4; }
    __syncthreads();
    if (t < 5) {
      int s5 = 0;
      #pragma unroll
      for (int ww = 0; ww < 8; ++ww) s5 += sc[ww*5+t];
      ((int*)(ws + CNT_OFF))[ll * 5 + t] = s5;
    }
  } else {
    // Wt[5l+v][d] += F[j][d] over a 512-j block, reg accumulate + 5 atomics
    int* slab = (int*)smem;
    const int idx = bid - 156;           // 0..159
    const int ll = idx >> 3, jblk = idx & 7;
    const int j0 = jblk * 512;
    slab[t] = lab[(j0 + t) * 20 + ll];
    __syncthreads();
    const int d = t & 255, half = t >> 8;
    const int base = half * 256;
    float a0 = 0, a1 = 0, a2 = 0, a3 = 0, a4 = 0;
    #pragma unroll 16
    for (int jj = 0; jj < 256; ++jj) {
      const int v = slab[base + jj];
      const float x = F[(size_t)(j0 + base + jj) * 256 + d];
      a0 += (v == 0) ? x : 0.f;
      a1 += (v == 1) ? x : 0.f;
      a2 += (v == 2) ? x : 0.f;
      a3 += (v == 3) ? x : 0.f;
      a4 += (v == 4) ? x : 0.f;
    }
    float* Wt = (float*)(ws + WT_OFF);
    atomicAdd(Wt + (ll * 5 + 0) * 256 + d, a0);
    atomicAdd(Wt + (ll * 5 + 1) * 256 + d, a1);
    atomicAdd(Wt + (ll * 5 + 2) * 256 + d, a2);
    atomicAdd(Wt + (ll * 5 + 3) * 256 + d, a3);
    atomicAdd(Wt + (ll * 5 + 4) * 256 + d, a4);
  }
}

// ---- final: per-row lp+m bucketing (O(B*L)) + last-block norms & scalar ----
__global__ __launch_bounds__(256) void k_final(const int* __restrict__ lab,
                                               unsigned char* __restrict__ ws,
                                               float* __restrict__ out) {
  __shared__ float sLPM[100], sC[100], wn2[100];
  __shared__ int isLast;
  const int t = threadIdx.x;
  if (t < 100) { sLPM[t] = 0.f; sC[t] = 0.f; }
  __syncthreads();
  const int i = blockIdx.x * 256 + t;
  const float m = ordinv(((const unsigned int*)(ws + MP_OFF))[i]);
  const float e = ((const float*)(ws + EP_OFF))[i];
  const float c = ((const float*)(ws + CV_OFF))[i];
  const float lp = logf(e * __expf(c - m) + 1e-20f);
  const float val = lp + m;
  #pragma unroll
  for (int ll = 0; ll < 20; ++ll) {
    const int v = lab[i * 20 + ll];
    atomicAdd(&sLPM[ll * 5 + v], val);
    atomicAdd(&sC[ll * 5 + v], c);
  }
  __syncthreads();
  float* ACC = (float*)(ws + ACC_OFF);
  if (t < 100) {
    atomicAdd(ACC + t, sLPM[t]);
    atomicAdd(ACC + 100 + t, sC[t]);
  }
  __syncthreads();
  if (t == 0) {
    __threadfence();
    unsigned int done = atomicAdd((unsigned int*)(ws + ACC_OFF + 800), 1u);
    isLast = (done == 15);
  }
  __syncthreads();
  if (isLast) {
    // ||Wt[lv]||^2: wave-per-row
    const int w = t >> 6, l = t & 63;
    const float* Wt = (const float*)(ws + WT_OFF);
    for (int row = w; row < 100; row += 4) {
      const float4 q = *(const float4*)(Wt + row * 256 + l * 4);
      float s = q.x * q.x + q.y * q.y + q.z * q.z + q.w * q.w;
      #pragma unroll
      for (int off = 1; off < 64; off <<= 1) s += __shfl_xor(s, off, 64);
      if (l == 0) wn2[row] = s;
    }
    __syncthreads();
    if (t == 0) {
      const int* cnts = (const int*)(ws + CNT_OFF);
      float loss = 0.f;
      for (int ll = 0; ll < 20; ++ll) {
        float ls = 0.f, singles = 0.f;
        for (int v = 0; v < 5; ++v) {
          const int idx = ll * 5 + v;
          const int cnt = cnts[idx];
          if (cnt >= 2) {
            const float Ls = __hip_atomic_load(ACC + idx, __ATOMIC_RELAXED, __HIP_MEMORY_SCOPE_AGENT);
            const float Cs = __hip_atomic_load(ACC + 100 + idx, __ATOMIC_RELAXED, __HIP_MEMORY_SCOPE_AGENT);
            ls += Ls - (wn2[idx] * INVT - Cs) / (float)(cnt - 1);
          } else if (cnt == 1) {
            singles += 1.f;
          }
        }
        loss += ls / (4096.f - singles);
      }
      out[0] = loss * 0.05f;
    }
  }
}

extern "C" void kernel_launch(void* const* d_in, const int* in_sizes, int n_in,
                              void* d_out, int out_size, void* d_ws, size_t ws_size,
                              hipStream_t stream) {
  const float* F = (const float*)d_in[0];
  const int* lab = (const int*)d_in[1];
  unsigned char* ws = (unsigned char*)d_ws;
  float* out = (float*)d_out;
  hipMemsetAsync(ws + WT_OFF, 0, 0x22000, stream);   // Wt + ACC + MP + EP
  k_fused<<<316, 512, 0, stream>>>(F, lab, ws);      // 136 triangle GEMM + 20 counts + 160 Wt
  k_final<<<16, 256, 0, stream>>>(lab, ws, out);
}